// Round 3
// baseline (676.222 us; speedup 1.0000x reference)
//
#include <hip/hip_runtime.h>
#include <hip/hip_bf16.h>

typedef unsigned short ushort;
typedef unsigned int uint;
typedef __bf16 bf16x8 __attribute__((ext_vector_type(8)));
typedef float f32x4 __attribute__((ext_vector_type(4)));

#define LOG2E 1.4426950408889634f
#define MFMA16(a,b,c) __builtin_amdgcn_mfma_f32_16x16x32_bf16((a),(b),(c),0,0,0)

static __device__ __forceinline__ uint packbf(float lo, float hi) {
  union { __bf16 h[2]; uint u; } x;
  x.h[0] = (__bf16)lo; x.h[1] = (__bf16)hi;
  return x.u;
}
static __device__ __forceinline__ float upbf(uint w, int sh) {
  union { float f; uint u; } x; x.u = ((w >> sh) & 0xFFFFu) << 16; return x.f;
}

// ---------------------------------------------------------------------------
// cast 4 weight matrices [256x256] f32 -> bf16 (contiguous in wsW)
// ---------------------------------------------------------------------------
__global__ __launch_bounds__(256) void cast_weights(
    const float* __restrict__ W0, const float* __restrict__ W1,
    const float* __restrict__ W2, const float* __restrict__ W3,
    __bf16* __restrict__ out)
{
  const int which = blockIdx.y;
  const float* src = which == 0 ? W0 : which == 1 ? W1 : which == 2 ? W2 : W3;
  const int i = (blockIdx.x * 256 + threadIdx.x) * 4;
  f32x4 v = *(const f32x4*)(src + i);
  union { __bf16 h[4]; uint u[2]; } x;
  #pragma unroll
  for (int j = 0; j < 4; j++) x.h[j] = (__bf16)v[j];
  *(uint*)(out + (size_t)which * 65536 + i) = x.u[0];
  *(uint*)(out + (size_t)which * 65536 + i + 2) = x.u[1];
}

// ---------------------------------------------------------------------------
// GEMM: out[n][d] = sum_c A[n][c] * W[d][c] + bias[d]
// A: f32 (cast in-reg) or bf16; W: bf16; out: bf16 / f32 / bf16-transposed
// TRANS: write out as V^T [batch][256][4096] (batch = row>>12)
// block: 256 thr = 4 waves; block tile 64n x 128d; wave tile 32n x 64d
// ---------------------------------------------------------------------------
template<bool A_F32, bool OUT_F32, bool TRANS>
__global__ __launch_bounds__(256) void gemm256(
    const void* __restrict__ A_, const ushort* __restrict__ W,
    const float* __restrict__ bias, void* __restrict__ out_)
{
  const int wid = threadIdx.x >> 6;
  const int lane = threadIdx.x & 63;
  const int q = lane & 15, g = lane >> 4;
  const int nb = blockIdx.x * 64 + (wid >> 1) * 32;
  const int db = blockIdx.y * 128 + (wid & 1) * 64;

  f32x4 acc[2][4];
  #pragma unroll
  for (int a = 0; a < 2; a++)
    #pragma unroll
    for (int b = 0; b < 4; b++) acc[a][b] = f32x4{0.f,0.f,0.f,0.f};

  const ushort* W0 = W + (size_t)(db + q) * 256 + g * 8;

  #pragma unroll
  for (int c0 = 0; c0 < 256; c0 += 32) {
    bf16x8 a0, a1;
    if constexpr (A_F32) {
      const float* Ar0 = (const float*)A_ + (size_t)(nb + q) * 256 + g * 8 + c0;
      const float* Ar1 = (const float*)A_ + (size_t)(nb + 16 + q) * 256 + g * 8 + c0;
      f32x4 u0 = *(const f32x4*)Ar0, u1 = *(const f32x4*)(Ar0 + 4);
      f32x4 w0 = *(const f32x4*)Ar1, w1 = *(const f32x4*)(Ar1 + 4);
      #pragma unroll
      for (int j = 0; j < 4; j++) {
        a0[j] = (__bf16)u0[j]; a0[4 + j] = (__bf16)u1[j];
        a1[j] = (__bf16)w0[j]; a1[4 + j] = (__bf16)w1[j];
      }
    } else {
      const ushort* Ar0 = (const ushort*)A_ + (size_t)(nb + q) * 256 + g * 8 + c0;
      const ushort* Ar1 = (const ushort*)A_ + (size_t)(nb + 16 + q) * 256 + g * 8 + c0;
      a0 = *(const bf16x8*)Ar0;
      a1 = *(const bf16x8*)Ar1;
    }
    #pragma unroll
    for (int df = 0; df < 4; df++) {
      bf16x8 w = *(const bf16x8*)(W0 + df * 16 * 256 + c0);
      acc[0][df] = MFMA16(a0, w, acc[0][df]);
      acc[1][df] = MFMA16(a1, w, acc[1][df]);
    }
  }
  #pragma unroll
  for (int df = 0; df < 4; df++) {
    float bv = bias[db + df * 16 + q];
    #pragma unroll
    for (int nf = 0; nf < 2; nf++)
      #pragma unroll
      for (int r = 0; r < 4; r++) {
        int row = nb + nf * 16 + g * 4 + r;
        int d = db + df * 16 + q;
        float val = acc[nf][df][r] + bv;
        if constexpr (TRANS) {
          ((__bf16*)out_)[(size_t)(row >> 12) * 1048576 + (size_t)d * 4096 + (row & 4095)]
              = (__bf16)val;
        } else if constexpr (OUT_F32) {
          ((float*)out_)[(size_t)row * 256 + d] = val;
        } else {
          ((__bf16*)out_)[(size_t)row * 256 + d] = (__bf16)val;
        }
      }
  }
}

// ---------------------------------------------------------------------------
// Flash attention, split-K x4 with in-block combine.
// grid: 1024 blocks (batch = bid&3); block owns 16 q rows; wave w owns keys
// [w*1024,(w+1)*1024) as 32 tiles of 32. No LDS staging in main loop.
// Swapped QK^T: S^T = mfma(K, Q): lane holds q-col = lane&15, rows = keys.
// ---------------------------------------------------------------------------
__global__ __launch_bounds__(256, 4) void attn_kernel(
    const ushort* __restrict__ Q, const ushort* __restrict__ K,
    const ushort* __restrict__ VT,   // bf16 [4][256][4096]
    const float* __restrict__ kp, const float* __restrict__ ka,
    const int* __restrict__ iter_idx,
    __bf16* __restrict__ matched,    // ws bf16 [B*4096][256]
    float* __restrict__ out_flow, float* __restrict__ out_conf)
{
  __shared__ float stats[4][16][4];   // [wave][q][m,l,u,v]
  __shared__ float linv[16];
  __shared__ uint oxch[4][8][264];    // [wave][rowpair][d] packed bf16, pad 264

  const int tid = threadIdx.x;
  const int wid = tid >> 6, lane = tid & 63;
  const int q = lane & 15, g = lane >> 4;
  const int batch = blockIdx.x & 3;        // XCD k hosts batch k&3 (L2 locality)
  const int qt = blockIdx.x >> 2;
  const int qrow = batch * 4096 + qt * 16;

  const int idx = *iter_idx;
  const float win = (idx == 0) ? 64.0f : fmaxf(4.0f, ldexpf(32.0f, 1 - idx));

  // Q fragments (B operand of swapped QK): col q = lane&15
  bf16x8 qf[8];
  const ushort* qptr = Q + (size_t)(qrow + q) * 256 + g * 8;
  #pragma unroll
  for (int mf = 0; mf < 8; mf++) qf[mf] = *(const bf16x8*)(qptr + mf * 32);

  const float2* kp2 = (const float2*)kp;
  const float pu = kp2[qrow + q].x;
  const float pv = kp2[qrow + q].y;

  f32x4 O[16];
  #pragma unroll
  for (int i = 0; i < 16; i++) O[i] = f32x4{0.f,0.f,0.f,0.f};
  float m_run = -1e9f, l_run = 0.f, u_run = 0.f, v_run = 0.f;

  const ushort* Kbase = K + (size_t)batch * 4096 * 256;
  const ushort* VTb = VT + (size_t)batch * 1048576;
  const float2* ka2 = (const float2*)ka + (size_t)batch * 4096;

  for (int t = 0; t < 32; t++) {
    const int kb = wid * 1024 + t * 32;   // local key base within batch

    // S^T = K . Q^T  (two 16-key fragments, split accumulators for ILP)
    const ushort* k0p = Kbase + (size_t)(kb + q) * 256 + g * 8;
    const ushort* k1p = Kbase + (size_t)(kb + 16 + q) * 256 + g * 8;
    f32x4 s0a = {0.f,0.f,0.f,0.f}, s0b = {0.f,0.f,0.f,0.f};
    f32x4 s1a = {0.f,0.f,0.f,0.f}, s1b = {0.f,0.f,0.f,0.f};
    #pragma unroll
    for (int mf = 0; mf < 8; mf += 2) {
      bf16x8 ka0 = *(const bf16x8*)(k0p + mf * 32);
      bf16x8 kb0 = *(const bf16x8*)(k0p + (mf + 1) * 32);
      bf16x8 ka1 = *(const bf16x8*)(k1p + mf * 32);
      bf16x8 kb1 = *(const bf16x8*)(k1p + (mf + 1) * 32);
      s0a = MFMA16(ka0, qf[mf], s0a);
      s0b = MFMA16(kb0, qf[mf + 1], s0b);
      s1a = MFMA16(ka1, qf[mf], s1a);
      s1b = MFMA16(kb1, qf[mf + 1], s1b);
    }

    // mask + scale; keys for this lane: frag0 k=4g+r, frag1 k=16+4g+r
    float aus[8], avs[8], sv[8];
    #pragma unroll
    for (int r = 0; r < 4; r++) {
      float2 c0 = ka2[kb + 4 * g + r];
      aus[r] = c0.x; avs[r] = c0.y;
      float du = fabsf(pu - aus[r]), dv = fabsf(pv - avs[r]);
      float sr = s0a[r] + s0b[r];
      sv[r] = (fmaxf(du, dv) < win) ? sr * 0.0625f : -1e9f;

      float2 c1 = ka2[kb + 16 + 4 * g + r];
      aus[4 + r] = c1.x; avs[4 + r] = c1.y;
      du = fabsf(pu - aus[4 + r]); dv = fabsf(pv - avs[4 + r]);
      sr = s1a[r] + s1b[r];
      sv[4 + r] = (fmaxf(du, dv) < win) ? sr * 0.0625f : -1e9f;
    }

    // online softmax (per column q, spread over 4 lane groups)
    float mt = fmaxf(fmaxf(fmaxf(sv[0], sv[1]), fmaxf(sv[2], sv[3])),
                     fmaxf(fmaxf(sv[4], sv[5]), fmaxf(sv[6], sv[7])));
    mt = fmaxf(mt, __shfl_xor(mt, 16));
    mt = fmaxf(mt, __shfl_xor(mt, 32));
    if (__any(mt > m_run)) {
      float m_new = fmaxf(m_run, mt);
      float scale = exp2f((m_run - m_new) * LOG2E);
      l_run *= scale; u_run *= scale; v_run *= scale;
      float s_r[4];
      #pragma unroll
      for (int r = 0; r < 4; r++) s_r[r] = __shfl(scale, 4 * g + r);
      #pragma unroll
      for (int df = 0; df < 16; df++)
        #pragma unroll
        for (int r = 0; r < 4; r++) O[df][r] *= s_r[r];
      m_run = m_new;
    }

    float p[8];
    #pragma unroll
    for (int i = 0; i < 8; i++) p[i] = exp2f((sv[i] - m_run) * LOG2E);
    #pragma unroll
    for (int i = 0; i < 8; i++) {
      l_run += p[i];
      u_run += p[i] * aus[i];
      v_run += p[i] * avs[i];
    }

    // pack P^T(C layout) -> A-operand layout via lane exchange
    uint d0 = packbf(p[0], p[1]), d1 = packbf(p[2], p[3]);
    uint d2 = packbf(p[4], p[5]), d3 = packbf(p[6], p[7]);
    int srcA = q + ((g & 1) << 5);
    int srcB = srcA + 16;
    uint x0 = (uint)__shfl((int)d0, srcA), x1 = (uint)__shfl((int)d1, srcA);
    uint x2 = (uint)__shfl((int)d0, srcB), x3 = (uint)__shfl((int)d1, srcB);
    uint y0 = (uint)__shfl((int)d2, srcA), y1 = (uint)__shfl((int)d3, srcA);
    uint y2 = (uint)__shfl((int)d2, srcB), y3 = (uint)__shfl((int)d3, srcB);
    union { uint i[4]; bf16x8 v; } af;
    bool lo = (g < 2);
    af.i[0] = lo ? x0 : y0; af.i[1] = lo ? x1 : y1;
    af.i[2] = lo ? x2 : y2; af.i[3] = lo ? x3 : y3;

    // PV: O += P * V^T-frag  (B-frags contiguous from pre-transposed V^T)
    #pragma unroll
    for (int df = 0; df < 16; df++) {
      bf16x8 vf = *(const bf16x8*)(VTb + (size_t)(df * 16 + q) * 4096 + kb + g * 8);
      O[df] = MFMA16(af.v, vf, O[df]);
    }
  }

  // per-wave reduction across the 4 lane groups
  l_run += __shfl_xor(l_run, 16); l_run += __shfl_xor(l_run, 32);
  u_run += __shfl_xor(u_run, 16); u_run += __shfl_xor(u_run, 32);
  v_run += __shfl_xor(v_run, 16); v_run += __shfl_xor(v_run, 32);

  if (g == 0) {
    stats[wid][q][0] = m_run; stats[wid][q][1] = l_run;
    stats[wid][q][2] = u_run; stats[wid][q][3] = v_run;
  }
  __syncthreads();

  // wave 0: combined stats -> flow/conf outputs + 1/l*
  if (wid == 0 && lane < 16) {
    float m0 = stats[0][q][0], m1 = stats[1][q][0];
    float m2 = stats[2][q][0], m3 = stats[3][q][0];
    float ms = fmaxf(fmaxf(m0, m1), fmaxf(m2, m3));
    float s0 = exp2f((m0 - ms) * LOG2E), s1 = exp2f((m1 - ms) * LOG2E);
    float s2 = exp2f((m2 - ms) * LOG2E), s3 = exp2f((m3 - ms) * LOG2E);
    float ls = s0 * stats[0][q][1] + s1 * stats[1][q][1]
             + s2 * stats[2][q][1] + s3 * stats[3][q][1];
    float us = s0 * stats[0][q][2] + s1 * stats[1][q][2]
             + s2 * stats[2][q][2] + s3 * stats[3][q][2];
    float vs = s0 * stats[0][q][3] + s1 * stats[1][q][3]
             + s2 * stats[2][q][3] + s3 * stats[3][q][3];
    float il = 1.0f / ls;
    linv[q] = il;
    float conf = (ms > -5e8f) ? 1.0f : 0.0f;
    int row = qrow + q;
    float fu = (us * il - pu) * conf, fv = (vs * il - pv) * conf;
    ((float2*)out_flow)[row] = float2{fu, fv};
    out_conf[row] = conf;
  }

  // every wave: scale own O to the combined max, write packed bf16 to LDS
  {
    float m0 = stats[0][q][0], m1 = stats[1][q][0];
    float m2 = stats[2][q][0], m3 = stats[3][q][0];
    float ms = fmaxf(fmaxf(m0, m1), fmaxf(m2, m3));
    float scale_q = exp2f((m_run - ms) * LOG2E);
    float s_r[4];
    #pragma unroll
    for (int r = 0; r < 4; r++) s_r[r] = __shfl(scale_q, 4 * g + r);
    #pragma unroll
    for (int df = 0; df < 16; df++) {
      f32x4 o = O[df];
      o[0] *= s_r[0]; o[1] *= s_r[1]; o[2] *= s_r[2]; o[3] *= s_r[3];
      oxch[wid][2 * g + 0][df * 16 + q] = packbf(o[0], o[1]);
      oxch[wid][2 * g + 1][df * 16 + q] = packbf(o[2], o[3]);
    }
  }
  __syncthreads();

  // combine the 4 partials and write matched
  {
    const int rr = tid >> 4, dl = tid & 15;
    const int rp = rr >> 1, sh = (rr & 1) << 4;
    const float il = linv[rr];
    __bf16* mrow = matched + (size_t)(qrow + rr) * 256;
    #pragma unroll
    for (int j = 0; j < 16; j++) {
      int dw = dl + 16 * j;
      float s = upbf(oxch[0][rp][dw], sh) + upbf(oxch[1][rp][dw], sh)
              + upbf(oxch[2][rp][dw], sh) + upbf(oxch[3][rp][dw], sh);
      mrow[dw] = (__bf16)(s * il);
    }
  }
}

// ---------------------------------------------------------------------------
// geo MLP: h = silu(geo_in @ Wg1^T + bg1); geo = h @ Wg2^T + bg2
// ---------------------------------------------------------------------------
__global__ __launch_bounds__(256) void geo_kernel(
    const float* __restrict__ flow, const float* __restrict__ conf_in,
    const float* __restrict__ Wg1, const float* __restrict__ bg1,
    const float* __restrict__ Wg2, const float* __restrict__ bg2,
    float* __restrict__ out_geo)
{
  __shared__ float w1[32][3], b1[32], b2[32];
  __shared__ __align__(16) float w2[32][32];
  int tid = threadIdx.x;
  for (int i = tid; i < 96; i += 256) w1[i / 3][i % 3] = Wg1[i];
  if (tid < 32) { b1[tid] = bg1[tid]; b2[tid] = bg2[tid]; }
  for (int i = tid; i < 1024; i += 256) w2[i / 32][i % 32] = Wg2[i];
  __syncthreads();

  int row = blockIdx.x * 256 + tid;
  float2 f = ((const float2*)flow)[row];
  float c = conf_in[row];
  float h[32];
  #pragma unroll
  for (int j = 0; j < 32; j++) {
    float x = w1[j][0] * f.x + w1[j][1] * f.y + w1[j][2] * c + b1[j];
    h[j] = x / (1.f + __expf(-x));
  }
  #pragma unroll
  for (int o = 0; o < 32; o += 2) {
    float s0 = b2[o], s1 = b2[o + 1];
    #pragma unroll
    for (int j = 0; j < 32; j += 4) {
      f32x4 wa = *(const f32x4*)&w2[o][j];
      f32x4 wb = *(const f32x4*)&w2[o + 1][j];
      s0 += wa[0]*h[j] + wa[1]*h[j+1] + wa[2]*h[j+2] + wa[3]*h[j+3];
      s1 += wb[0]*h[j] + wb[1]*h[j+1] + wb[2]*h[j+2] + wb[3]*h[j+3];
    }
    ((float2*)out_geo)[((size_t)row * 32 + o) >> 1] = float2{s0, s1};
  }
}

// ---------------------------------------------------------------------------
extern "C" void kernel_launch(void* const* d_in, const int* in_sizes, int n_in,
                              void* d_out, int out_size, void* d_ws, size_t ws_size,
                              hipStream_t stream) {
  const float* nodes_t  = (const float*)d_in[0];
  const float* nodes_t1 = (const float*)d_in[1];
  const float* kpred    = (const float*)d_in[2];
  const float* kact     = (const float*)d_in[3];
  const float* Wq = (const float*)d_in[4];  const float* bq = (const float*)d_in[5];
  const float* Wk = (const float*)d_in[6];  const float* bk = (const float*)d_in[7];
  const float* Wv = (const float*)d_in[8];  const float* bv = (const float*)d_in[9];
  const float* Wm = (const float*)d_in[10]; const float* bm = (const float*)d_in[11];
  const float* Wg1= (const float*)d_in[12]; const float* bg1= (const float*)d_in[13];
  const float* Wg2= (const float*)d_in[14]; const float* bg2= (const float*)d_in[15];
  const int* iter = (const int*)d_in[16];

  float* out_merged = (float*)d_out;                 // 4*4096*256
  float* out_geo  = out_merged + 4 * 4096 * 256;     // 4*4096*32
  float* out_flow = out_geo + 4 * 4096 * 32;         // 4*4096*2
  float* out_conf = out_flow + 4 * 4096 * 2;         // 4*4096

  ushort* wsQ  = (ushort*)d_ws;        // bf16 4194304 el each
  ushort* wsK  = wsQ + 4194304;
  ushort* wsVT = wsK + 4194304;        // V^T [4][256][4096]
  ushort* wsM  = wsVT + 4194304;
  ushort* wsW  = wsM + 4194304;        // bf16 4*65536 (Wq,Wk,Wv,Wm)

  dim3 cg(64, 4, 1);
  cast_weights<<<cg, 256, 0, stream>>>(Wq, Wk, Wv, Wm, (__bf16*)wsW);

  dim3 gg(256, 2, 1);
  gemm256<true,  false, false><<<gg, 256, 0, stream>>>(nodes_t,  wsW,          bq, wsQ);
  gemm256<true,  false, false><<<gg, 256, 0, stream>>>(nodes_t1, wsW + 65536,  bk, wsK);
  gemm256<true,  false, true ><<<gg, 256, 0, stream>>>(nodes_t1, wsW + 131072, bv, wsVT);
  attn_kernel<<<1024, 256, 0, stream>>>(wsQ, wsK, wsVT, kpred, kact, iter,
                                        (__bf16*)wsM, out_flow, out_conf);
  gemm256<false, true,  false><<<gg, 256, 0, stream>>>(wsM, wsW + 196608, bm, out_merged);
  geo_kernel<<<64, 256, 0, stream>>>(out_flow, out_conf, Wg1, bg1, Wg2, bg2, out_geo);
}

// Round 4
// 338.682 us; speedup vs baseline: 1.9966x; 1.9966x over previous
//
#include <hip/hip_runtime.h>
#include <hip/hip_bf16.h>

typedef unsigned short ushort;
typedef unsigned int uint;
typedef __bf16 bf16x8 __attribute__((ext_vector_type(8)));
typedef float f32x4 __attribute__((ext_vector_type(4)));

#define LOG2E 1.4426950408889634f
#define MFMA16(a,b,c) __builtin_amdgcn_mfma_f32_16x16x32_bf16((a),(b),(c),0,0,0)

static __device__ __forceinline__ uint packbf(float lo, float hi) {
  union { __bf16 h[2]; uint u; } x;
  x.h[0] = (__bf16)lo; x.h[1] = (__bf16)hi;
  return x.u;
}
static __device__ __forceinline__ float upbf(uint w, int sh) {
  union { float f; uint u; } x; x.u = ((w >> sh) & 0xFFFFu) << 16; return x.f;
}
static __device__ __forceinline__ int cellof(float x) {
  int c = (int)(x * 0.015625f);           // /64
  return c < 0 ? 0 : (c > 9 ? 9 : c);
}

// ---------------------------------------------------------------------------
// zero the small counters region
// ---------------------------------------------------------------------------
__global__ void zero_ws(int* __restrict__ hist, int* __restrict__ curs,
                        float* __restrict__ meanN)
{
  int t = threadIdx.x;
  for (int i = t; i < 1024; i += 256) { hist[i] = 0; curs[i] = 0; meanN[i] = 0.f; }
}

// ---------------------------------------------------------------------------
// cast 4 weight matrices [256x256] f32 -> bf16 (contiguous in wsW)
// ---------------------------------------------------------------------------
__global__ __launch_bounds__(256) void cast_weights(
    const float* __restrict__ W0, const float* __restrict__ W1,
    const float* __restrict__ W2, const float* __restrict__ W3,
    __bf16* __restrict__ out)
{
  const int which = blockIdx.y;
  const float* src = which == 0 ? W0 : which == 1 ? W1 : which == 2 ? W2 : W3;
  const int i = (blockIdx.x * 256 + threadIdx.x) * 4;
  f32x4 v = *(const f32x4*)(src + i);
  union { __bf16 h[4]; uint u[2]; } x;
  #pragma unroll
  for (int j = 0; j < 4; j++) x.h[j] = (__bf16)v[j];
  *(uint*)(out + (size_t)which * 65536 + i) = x.u[0];
  *(uint*)(out + (size_t)which * 65536 + i + 2) = x.u[1];
}

// ---------------------------------------------------------------------------
// histogram points into 10x10 cells. type0 = queries(kpred), type1 = keys(kact)
// hist layout [8][128]: seg = type*4 + batch
// ---------------------------------------------------------------------------
__global__ __launch_bounds__(256) void hist_kernel(
    const float* __restrict__ kpred, const float* __restrict__ kact,
    int* __restrict__ hist, int* __restrict__ cellpt)
{
  int p = blockIdx.x * 256 + threadIdx.x;     // 0..32767
  int type = p >> 14, idx = p & 16383;
  const float2 c = ((const float2*)(type == 0 ? kpred : kact))[idx];
  int cell = cellof(c.x) * 10 + cellof(c.y);
  int b = idx >> 12;
  atomicAdd(&hist[(type * 4 + b) * 128 + cell], 1);
  cellpt[type * 16384 + idx] = cell;
}

// ---------------------------------------------------------------------------
// exclusive scan of 8 segments x 100 cells -> start[seg][0..100], cursor copy
// ---------------------------------------------------------------------------
__global__ __launch_bounds__(256) void scan_kernel(
    const int* __restrict__ hist, int* __restrict__ strt, int* __restrict__ curs)
{
  __shared__ int sh[1024];
  int t = threadIdx.x;
  for (int i = t; i < 1024; i += 256) sh[i] = hist[i];
  __syncthreads();
  if (t < 8) {
    int run = 0;
    for (int c = 0; c < 100; c++) {
      strt[t * 128 + c] = run;
      curs[t * 128 + c] = run;
      run += sh[t * 128 + c];
    }
    strt[t * 128 + 100] = run;   // sentinel (=4096)
  }
}

// ---------------------------------------------------------------------------
// scatter: sorted query/key index arrays, inverse key perm, sorted key coords
// ---------------------------------------------------------------------------
__global__ __launch_bounds__(256) void scatter_kernel(
    const float* __restrict__ kact, const int* __restrict__ cellpt,
    int* __restrict__ curs,
    int* __restrict__ sq, int* __restrict__ sk, int* __restrict__ invk,
    float* __restrict__ kaS)
{
  int p = blockIdx.x * 256 + threadIdx.x;
  int type = p >> 14, idx = p & 16383;
  int b = idx >> 12, n = idx & 4095;
  int cell = cellpt[type * 16384 + idx];
  int pos = atomicAdd(&curs[(type * 4 + b) * 128 + cell], 1);
  if (type == 0) {
    sq[b * 4096 + pos] = n;
  } else {
    sk[b * 4096 + pos] = n;
    invk[b * 4096 + n] = pos;
    ((float2*)kaS)[b * 4096 + pos] = ((const float2*)kact)[idx];
  }
}

// ---------------------------------------------------------------------------
// column means of nodes_t1 per batch (sum; /4096 folded into vmean_kernel)
// ---------------------------------------------------------------------------
__global__ __launch_bounds__(256) void meansum_kernel(
    const float* __restrict__ nodes_t1, float* __restrict__ meanN)
{
  int b = blockIdx.y, chunk = blockIdx.x, c = threadIdx.x;
  const float* base = nodes_t1 + ((size_t)b * 4096 + chunk * 256) * 256 + c;
  float s = 0.f;
  for (int r = 0; r < 256; r++) s += base[(size_t)r * 256];
  atomicAdd(&meanN[b * 256 + c], s);
}

__global__ __launch_bounds__(256) void vmean_kernel(
    const float* __restrict__ meanN, const float* __restrict__ Wv,
    const float* __restrict__ bv, float* __restrict__ Vmean)
{
  __shared__ float mn[256];
  int b = blockIdx.x, d = threadIdx.x;
  mn[d] = meanN[b * 256 + d] * (1.0f / 4096.0f);
  __syncthreads();
  float s = bv[d];
  const float* w = Wv + (size_t)d * 256;
  for (int c = 0; c < 256; c++) s += mn[c] * w[c];
  Vmean[b * 256 + d] = s;
}

// ---------------------------------------------------------------------------
// GEMM: out[n][d] = sum_c A[n][c] * W[d][c] + bias[d]
// MODE 0: bf16 row-major out. MODE 1: f32 row-major out.
// MODE 2: bf16 out at VT_s[b][d][invk[row]]  (perm-transposed, sorted keys)
// block: 256 thr = 4 waves; block tile 64n x 128d; wave tile 32n x 64d
// ---------------------------------------------------------------------------
template<bool A_F32, int MODE>
__global__ __launch_bounds__(256) void gemm256(
    const void* __restrict__ A_, const ushort* __restrict__ W,
    const float* __restrict__ bias, void* __restrict__ out_,
    const int* __restrict__ invk)
{
  const int wid = threadIdx.x >> 6;
  const int lane = threadIdx.x & 63;
  const int q = lane & 15, g = lane >> 4;
  const int nb = blockIdx.x * 64 + (wid >> 1) * 32;
  const int db = blockIdx.y * 128 + (wid & 1) * 64;

  f32x4 acc[2][4];
  #pragma unroll
  for (int a = 0; a < 2; a++)
    #pragma unroll
    for (int b = 0; b < 4; b++) acc[a][b] = f32x4{0.f,0.f,0.f,0.f};

  const ushort* W0 = W + (size_t)(db + q) * 256 + g * 8;

  #pragma unroll
  for (int c0 = 0; c0 < 256; c0 += 32) {
    bf16x8 a0, a1;
    if constexpr (A_F32) {
      const float* Ar0 = (const float*)A_ + (size_t)(nb + q) * 256 + g * 8 + c0;
      const float* Ar1 = (const float*)A_ + (size_t)(nb + 16 + q) * 256 + g * 8 + c0;
      f32x4 u0 = *(const f32x4*)Ar0, u1 = *(const f32x4*)(Ar0 + 4);
      f32x4 w0 = *(const f32x4*)Ar1, w1 = *(const f32x4*)(Ar1 + 4);
      #pragma unroll
      for (int j = 0; j < 4; j++) {
        a0[j] = (__bf16)u0[j]; a0[4 + j] = (__bf16)u1[j];
        a1[j] = (__bf16)w0[j]; a1[4 + j] = (__bf16)w1[j];
      }
    } else {
      const ushort* Ar0 = (const ushort*)A_ + (size_t)(nb + q) * 256 + g * 8 + c0;
      const ushort* Ar1 = (const ushort*)A_ + (size_t)(nb + 16 + q) * 256 + g * 8 + c0;
      a0 = *(const bf16x8*)Ar0;
      a1 = *(const bf16x8*)Ar1;
    }
    #pragma unroll
    for (int df = 0; df < 4; df++) {
      bf16x8 w = *(const bf16x8*)(W0 + df * 16 * 256 + c0);
      acc[0][df] = MFMA16(a0, w, acc[0][df]);
      acc[1][df] = MFMA16(a1, w, acc[1][df]);
    }
  }
  #pragma unroll
  for (int df = 0; df < 4; df++) {
    float bv = bias[db + df * 16 + q];
    #pragma unroll
    for (int nf = 0; nf < 2; nf++)
      #pragma unroll
      for (int r = 0; r < 4; r++) {
        int row = nb + nf * 16 + g * 4 + r;
        int d = db + df * 16 + q;
        float val = acc[nf][df][r] + bv;
        if constexpr (MODE == 2) {
          int pos = invk[row];
          ((__bf16*)out_)[(size_t)(row >> 12) * 1048576 + (size_t)d * 4096 + pos]
              = (__bf16)val;
        } else if constexpr (MODE == 1) {
          ((float*)out_)[(size_t)row * 256 + d] = val;
        } else {
          ((__bf16*)out_)[(size_t)row * 256 + d] = (__bf16)val;
        }
      }
  }
}

// ---------------------------------------------------------------------------
// Sparse flash attention over cell-sorted queries/keys, split-K x4 in-block.
// grid: 1024 blocks (batch = bid&3); block = 16 sorted q rows; waves stride
// 32-key tiles within the bbox cell runs. Swapped QK^T as before.
// ---------------------------------------------------------------------------
__global__ __launch_bounds__(256, 4) void attn_kernel(
    const ushort* __restrict__ Q, const ushort* __restrict__ K,
    const ushort* __restrict__ VT,   // bf16 [4][256][4096] sorted-key order
    const float* __restrict__ kp,
    const int* __restrict__ iter_idx,
    const int* __restrict__ sq, const int* __restrict__ sk,
    const int* __restrict__ strt,    // [8][128], key segs at +4*128
    const float* __restrict__ kaS,   // sorted key coords float2
    const float* __restrict__ Vmean,
    __bf16* __restrict__ matched,
    float* __restrict__ out_flow, float* __restrict__ out_conf)
{
  __shared__ float stats[4][16][4];   // [wave][q][m,l,u,v]
  __shared__ float linv[16];
  __shared__ int qidx[16];
  __shared__ uint oxch[4][8][264];    // [wave][rowpair][dword] packed bf16

  const int tid = threadIdx.x;
  const int wid = tid >> 6, lane = tid & 63;
  const int q = lane & 15, g = lane >> 4;
  const int batch = blockIdx.x & 3;
  const int qt = blockIdx.x >> 2;

  const int idx = *iter_idx;
  const float win = (idx == 0) ? 64.0f : fmaxf(4.0f, ldexpf(32.0f, 1 - idx));

  // sorted query for this lane's column
  const int qi = sq[batch * 4096 + qt * 16 + q];       // within-batch row
  const int qrow_g = batch * 4096 + qi;
  if (tid < 16) qidx[tid] = sq[batch * 4096 + qt * 16 + tid];

  bf16x8 qf[8];
  const ushort* qptr = Q + (size_t)qrow_g * 256 + g * 8;
  #pragma unroll
  for (int mf = 0; mf < 8; mf++) qf[mf] = *(const bf16x8*)(qptr + mf * 32);

  const float2 kpv = ((const float2*)kp)[qrow_g];
  const float pu = kpv.x, pv = kpv.y;

  // tile bbox over the 16 queries (lanes replicate across 16-groups)
  float mnu = pu, mxu = pu, mnv = pv, mxv = pv;
  #pragma unroll
  for (int off = 1; off < 16; off <<= 1) {
    mnu = fminf(mnu, __shfl_xor(mnu, off));
    mxu = fmaxf(mxu, __shfl_xor(mxu, off));
    mnv = fminf(mnv, __shfl_xor(mnv, off));
    mxv = fmaxf(mxv, __shfl_xor(mxv, off));
  }
  const int cu_lo = cellof(mnu), cu_hi = cellof(mxu);
  const int c0 = max(cellof(mnv) - 1, 0), c1 = min(cellof(mxv) + 1, 9);

  f32x4 O[16];
  #pragma unroll
  for (int i = 0; i < 16; i++) O[i] = f32x4{0.f,0.f,0.f,0.f};
  float m_run = -1e9f, l_run = 0.f, u_run = 0.f, v_run = 0.f;

  const ushort* Kbase = K + (size_t)batch * 4096 * 256;
  const ushort* VTb = VT + (size_t)batch * 1048576;
  const float2* kasb = (const float2*)kaS + (size_t)batch * 4096;
  const int* skb = sk + batch * 4096;
  const int* kst = strt + (4 + batch) * 128;

  for (int cu = cu_lo - 1; cu <= cu_hi + 1; ++cu) {
    if ((unsigned)cu > 9u) continue;
    const int ks = kst[cu * 10 + c0];
    const int ke = kst[cu * 10 + c1 + 1];
    for (int t = (ks & ~31) + wid * 32; t < ke; t += 128) {
      // gather K fragment rows (invalid -> row 0, masked later)
      const int j0 = t + q, j1 = j0 + 16;
      const int ki0 = (j0 >= ks && j0 < ke) ? skb[j0] : 0;
      const int ki1 = (j1 >= ks && j1 < ke) ? skb[j1] : 0;
      const ushort* k0p = Kbase + (size_t)ki0 * 256 + g * 8;
      const ushort* k1p = Kbase + (size_t)ki1 * 256 + g * 8;
      f32x4 s0a = {0.f,0.f,0.f,0.f}, s0b = {0.f,0.f,0.f,0.f};
      f32x4 s1a = {0.f,0.f,0.f,0.f}, s1b = {0.f,0.f,0.f,0.f};
      #pragma unroll
      for (int mf = 0; mf < 8; mf += 2) {
        bf16x8 ka0 = *(const bf16x8*)(k0p + mf * 32);
        bf16x8 kb0 = *(const bf16x8*)(k0p + (mf + 1) * 32);
        bf16x8 ka1 = *(const bf16x8*)(k1p + mf * 32);
        bf16x8 kb1 = *(const bf16x8*)(k1p + (mf + 1) * 32);
        s0a = MFMA16(ka0, qf[mf], s0a);
        s0b = MFMA16(kb0, qf[mf + 1], s0b);
        s1a = MFMA16(ka1, qf[mf], s1a);
        s1b = MFMA16(kb1, qf[mf + 1], s1b);
      }

      float aus[8], avs[8], sv[8];
      #pragma unroll
      for (int r = 0; r < 4; r++) {
        int jr = t + 4 * g + r;
        float2 cc = kasb[jr];
        aus[r] = cc.x; avs[r] = cc.y;
        bool val = (jr >= ks && jr < ke);
        float du = fabsf(pu - cc.x), dv = fabsf(pv - cc.y);
        float sr = s0a[r] + s0b[r];
        sv[r] = (val && fmaxf(du, dv) < win) ? sr * 0.0625f : -1e9f;

        int jr1 = jr + 16;
        float2 c1c = kasb[jr1];
        aus[4 + r] = c1c.x; avs[4 + r] = c1c.y;
        val = (jr1 >= ks && jr1 < ke);
        du = fabsf(pu - c1c.x); dv = fabsf(pv - c1c.y);
        sr = s1a[r] + s1b[r];
        sv[4 + r] = (val && fmaxf(du, dv) < win) ? sr * 0.0625f : -1e9f;
      }

      float mt = fmaxf(fmaxf(fmaxf(sv[0], sv[1]), fmaxf(sv[2], sv[3])),
                       fmaxf(fmaxf(sv[4], sv[5]), fmaxf(sv[6], sv[7])));
      mt = fmaxf(mt, __shfl_xor(mt, 16));
      mt = fmaxf(mt, __shfl_xor(mt, 32));
      if (__any(mt > m_run)) {
        float m_new = fmaxf(m_run, mt);
        float scale = exp2f((m_run - m_new) * LOG2E);
        l_run *= scale; u_run *= scale; v_run *= scale;
        float s_r[4];
        #pragma unroll
        for (int r = 0; r < 4; r++) s_r[r] = __shfl(scale, 4 * g + r);
        #pragma unroll
        for (int df = 0; df < 16; df++)
          #pragma unroll
          for (int r = 0; r < 4; r++) O[df][r] *= s_r[r];
        m_run = m_new;
      }

      float p[8];
      #pragma unroll
      for (int i = 0; i < 8; i++) p[i] = exp2f((sv[i] - m_run) * LOG2E);
      #pragma unroll
      for (int i = 0; i < 8; i++) {
        l_run += p[i];
        u_run += p[i] * aus[i];
        v_run += p[i] * avs[i];
      }

      // pack P^T(C layout) -> A-operand layout via lane exchange
      uint d0 = packbf(p[0], p[1]), d1 = packbf(p[2], p[3]);
      uint d2 = packbf(p[4], p[5]), d3 = packbf(p[6], p[7]);
      int srcA = q + ((g & 1) << 5);
      int srcB = srcA + 16;
      uint x0 = (uint)__shfl((int)d0, srcA), x1 = (uint)__shfl((int)d1, srcA);
      uint x2 = (uint)__shfl((int)d0, srcB), x3 = (uint)__shfl((int)d1, srcB);
      uint y0 = (uint)__shfl((int)d2, srcA), y1 = (uint)__shfl((int)d3, srcA);
      uint y2 = (uint)__shfl((int)d2, srcB), y3 = (uint)__shfl((int)d3, srcB);
      union { uint i[4]; bf16x8 v; } af;
      bool lo = (g < 2);
      af.i[0] = lo ? x0 : y0; af.i[1] = lo ? x1 : y1;
      af.i[2] = lo ? x2 : y2; af.i[3] = lo ? x3 : y3;

      #pragma unroll
      for (int df = 0; df < 16; df++) {
        bf16x8 vf = *(const bf16x8*)(VTb + (size_t)(df * 16 + q) * 4096 + t + g * 8);
        O[df] = MFMA16(af.v, vf, O[df]);
      }
    }
  }

  // per-wave reduction across the 4 lane groups
  l_run += __shfl_xor(l_run, 16); l_run += __shfl_xor(l_run, 32);
  u_run += __shfl_xor(u_run, 16); u_run += __shfl_xor(u_run, 32);
  v_run += __shfl_xor(v_run, 16); v_run += __shfl_xor(v_run, 32);

  if (g == 0) {
    stats[wid][q][0] = m_run; stats[wid][q][1] = l_run;
    stats[wid][q][2] = u_run; stats[wid][q][3] = v_run;
  }
  __syncthreads();

  // wave 0 lanes 0..15: combined stats -> flow/conf (scattered) + 1/l*
  if (wid == 0 && lane < 16) {
    float m0 = stats[0][q][0], m1 = stats[1][q][0];
    float m2 = stats[2][q][0], m3 = stats[3][q][0];
    float ms = fmaxf(fmaxf(m0, m1), fmaxf(m2, m3));
    float s0 = exp2f((m0 - ms) * LOG2E), s1 = exp2f((m1 - ms) * LOG2E);
    float s2 = exp2f((m2 - ms) * LOG2E), s3 = exp2f((m3 - ms) * LOG2E);
    float ls = s0 * stats[0][q][1] + s1 * stats[1][q][1]
             + s2 * stats[2][q][1] + s3 * stats[3][q][1];
    float us = s0 * stats[0][q][2] + s1 * stats[1][q][2]
             + s2 * stats[2][q][2] + s3 * stats[3][q][2];
    float vs = s0 * stats[0][q][3] + s1 * stats[1][q][3]
             + s2 * stats[2][q][3] + s3 * stats[3][q][3];
    bool degen = (ms <= -5e8f);
    float il = degen ? 0.f : 1.0f / ls;
    linv[q] = il;
    float conf = degen ? 0.f : 1.0f;
    int row = batch * 4096 + qi;
    float fu = (us * il - pu) * conf, fv = (vs * il - pv) * conf;
    ((float2*)out_flow)[row] = float2{fu, fv};
    out_conf[row] = conf;
  }

  // every wave: scale own O to combined max, write packed bf16 to LDS
  {
    float m0 = stats[0][q][0], m1 = stats[1][q][0];
    float m2 = stats[2][q][0], m3 = stats[3][q][0];
    float ms = fmaxf(fmaxf(m0, m1), fmaxf(m2, m3));
    float scale_q = exp2f((m_run - ms) * LOG2E);
    float s_r[4];
    #pragma unroll
    for (int r = 0; r < 4; r++) s_r[r] = __shfl(scale_q, 4 * g + r);
    #pragma unroll
    for (int df = 0; df < 16; df++) {
      f32x4 o = O[df];
      o[0] *= s_r[0]; o[1] *= s_r[1]; o[2] *= s_r[2]; o[3] *= s_r[3];
      oxch[wid][2 * g + 0][df * 16 + q] = packbf(o[0], o[1]);
      oxch[wid][2 * g + 1][df * 16 + q] = packbf(o[2], o[3]);
    }
  }
  __syncthreads();

  // combine 4 partials, write matched (scattered rows; Vmean if degenerate)
  {
    const int rr = tid >> 4, dl = tid & 15;
    const int rp = rr >> 1, sh = (rr & 1) << 4;
    const float il = linv[rr];
    const bool degen = (il == 0.f);
    const float* Vm = Vmean + batch * 256;
    __bf16* mrow = matched + ((size_t)batch * 4096 + qidx[rr]) * 256;
    #pragma unroll
    for (int j = 0; j < 16; j++) {
      int dw = dl + 16 * j;
      float s = upbf(oxch[0][rp][dw], sh) + upbf(oxch[1][rp][dw], sh)
              + upbf(oxch[2][rp][dw], sh) + upbf(oxch[3][rp][dw], sh);
      mrow[dw] = (__bf16)(degen ? Vm[dw] : s * il);
    }
  }
}

// ---------------------------------------------------------------------------
// geo MLP
// ---------------------------------------------------------------------------
__global__ __launch_bounds__(256) void geo_kernel(
    const float* __restrict__ flow, const float* __restrict__ conf_in,
    const float* __restrict__ Wg1, const float* __restrict__ bg1,
    const float* __restrict__ Wg2, const float* __restrict__ bg2,
    float* __restrict__ out_geo)
{
  __shared__ float w1[32][3], b1[32], b2[32];
  __shared__ __align__(16) float w2[32][32];
  int tid = threadIdx.x;
  for (int i = tid; i < 96; i += 256) w1[i / 3][i % 3] = Wg1[i];
  if (tid < 32) { b1[tid] = bg1[tid]; b2[tid] = bg2[tid]; }
  for (int i = tid; i < 1024; i += 256) w2[i / 32][i % 32] = Wg2[i];
  __syncthreads();

  int row = blockIdx.x * 256 + tid;
  float2 f = ((const float2*)flow)[row];
  float c = conf_in[row];
  float h[32];
  #pragma unroll
  for (int j = 0; j < 32; j++) {
    float x = w1[j][0] * f.x + w1[j][1] * f.y + w1[j][2] * c + b1[j];
    h[j] = x / (1.f + __expf(-x));
  }
  #pragma unroll
  for (int o = 0; o < 32; o += 2) {
    float s0 = b2[o], s1 = b2[o + 1];
    #pragma unroll
    for (int j = 0; j < 32; j += 4) {
      f32x4 wa = *(const f32x4*)&w2[o][j];
      f32x4 wb = *(const f32x4*)&w2[o + 1][j];
      s0 += wa[0]*h[j] + wa[1]*h[j+1] + wa[2]*h[j+2] + wa[3]*h[j+3];
      s1 += wb[0]*h[j] + wb[1]*h[j+1] + wb[2]*h[j+2] + wb[3]*h[j+3];
    }
    ((float2*)out_geo)[((size_t)row * 32 + o) >> 1] = float2{s0, s1};
  }
}

// ---------------------------------------------------------------------------
extern "C" void kernel_launch(void* const* d_in, const int* in_sizes, int n_in,
                              void* d_out, int out_size, void* d_ws, size_t ws_size,
                              hipStream_t stream) {
  const float* nodes_t  = (const float*)d_in[0];
  const float* nodes_t1 = (const float*)d_in[1];
  const float* kpred    = (const float*)d_in[2];
  const float* kact     = (const float*)d_in[3];
  const float* Wq = (const float*)d_in[4];  const float* bq = (const float*)d_in[5];
  const float* Wk = (const float*)d_in[6];  const float* bk = (const float*)d_in[7];
  const float* Wv = (const float*)d_in[8];  const float* bv = (const float*)d_in[9];
  const float* Wm = (const float*)d_in[10]; const float* bm = (const float*)d_in[11];
  const float* Wg1= (const float*)d_in[12]; const float* bg1= (const float*)d_in[13];
  const float* Wg2= (const float*)d_in[14]; const float* bg2= (const float*)d_in[15];
  const int* iter = (const int*)d_in[16];

  float* out_merged = (float*)d_out;                 // 4*4096*256
  float* out_geo  = out_merged + 4 * 4096 * 256;     // 4*4096*32
  float* out_flow = out_geo + 4 * 4096 * 32;         // 4*4096*2
  float* out_conf = out_flow + 4 * 4096 * 2;         // 4*4096

  ushort* wsQ   = (ushort*)d_ws;        // bf16 4194304 el each
  ushort* wsK   = wsQ + 4194304;
  ushort* wsVT  = wsK + 4194304;        // VT_s [4][256][4096] sorted keys
  ushort* wsM   = wsVT + 4194304;
  ushort* wsW   = wsM + 4194304;        // bf16 4*65536
  float*  kaS   = (float*)(wsW + 262144);   // 32768 f32
  float*  meanN = kaS + 32768;              // 1024
  float*  Vmean = meanN + 1024;             // 1024
  int*    hist  = (int*)(Vmean + 1024);     // 1024
  int*    strt  = hist + 1024;              // 1024
  int*    curs  = strt + 1024;              // 1024
  int*    cellpt= curs + 1024;              // 32768
  int*    sq    = cellpt + 32768;           // 16384
  int*    sk    = sq + 16384;               // 16384
  int*    invk  = sk + 16384;               // 16384

  zero_ws<<<1, 256, 0, stream>>>(hist, curs, meanN);
  dim3 cg(64, 4, 1);
  cast_weights<<<cg, 256, 0, stream>>>(Wq, Wk, Wv, Wm, (__bf16*)wsW);
  hist_kernel<<<128, 256, 0, stream>>>(kpred, kact, hist, cellpt);
  scan_kernel<<<1, 256, 0, stream>>>(hist, strt, curs);
  scatter_kernel<<<128, 256, 0, stream>>>(kact, cellpt, curs, sq, sk, invk, kaS);
  dim3 mg(16, 4, 1);
  meansum_kernel<<<mg, 256, 0, stream>>>(nodes_t1, meanN);
  vmean_kernel<<<4, 256, 0, stream>>>(meanN, Wv, bv, Vmean);

  dim3 gg(256, 2, 1);
  gemm256<true, 0><<<gg, 256, 0, stream>>>(nodes_t,  wsW,          bq, wsQ, nullptr);
  gemm256<true, 0><<<gg, 256, 0, stream>>>(nodes_t1, wsW + 65536,  bk, wsK, nullptr);
  gemm256<true, 2><<<gg, 256, 0, stream>>>(nodes_t1, wsW + 131072, bv, wsVT, invk);
  attn_kernel<<<1024, 256, 0, stream>>>(wsQ, wsK, wsVT, kpred, iter,
                                        sq, sk, strt, kaS, Vmean,
                                        (__bf16*)wsM, out_flow, out_conf);
  gemm256<false, 1><<<gg, 256, 0, stream>>>(wsM, wsW + 196608, bm, out_merged, nullptr);
  geo_kernel<<<64, 256, 0, stream>>>(out_flow, out_conf, Wg1, bg1, Wg2, bg2, out_geo);
}

// Round 5
// 267.502 us; speedup vs baseline: 2.5279x; 1.2661x over previous
//
#include <hip/hip_runtime.h>
#include <hip/hip_bf16.h>

typedef unsigned short ushort;
typedef unsigned int uint;
typedef __bf16 bf16x8 __attribute__((ext_vector_type(8)));
typedef float f32x4 __attribute__((ext_vector_type(4)));

#define LOG2E 1.4426950408889634f
#define MFMA16(a,b,c) __builtin_amdgcn_mfma_f32_16x16x32_bf16((a),(b),(c),0,0,0)

static __device__ __forceinline__ uint packbf(float lo, float hi) {
  union { __bf16 h[2]; uint u; } x;
  x.h[0] = (__bf16)lo; x.h[1] = (__bf16)hi;
  return x.u;
}
static __device__ __forceinline__ float upbf(uint w, int sh) {
  union { float f; uint u; } x; x.u = ((w >> sh) & 0xFFFFu) << 16; return x.f;
}
static __device__ __forceinline__ int cellof(float x) {
  int c = (int)(x * 0.015625f);           // /64
  return c < 0 ? 0 : (c > 9 ? 9 : c);
}

// ---------------------------------------------------------------------------
__global__ void zero_ws(int* __restrict__ hist, int* __restrict__ curs,
                        float* __restrict__ meanN)
{
  int t = threadIdx.x;
  for (int i = t; i < 1024; i += 256) { hist[i] = 0; curs[i] = 0; meanN[i] = 0.f; }
}

// ---------------------------------------------------------------------------
__global__ __launch_bounds__(256) void cast_weights(
    const float* __restrict__ W0, const float* __restrict__ W1,
    const float* __restrict__ W2, const float* __restrict__ W3,
    __bf16* __restrict__ out)
{
  const int which = blockIdx.y;
  const float* src = which == 0 ? W0 : which == 1 ? W1 : which == 2 ? W2 : W3;
  const int i = (blockIdx.x * 256 + threadIdx.x) * 4;
  f32x4 v = *(const f32x4*)(src + i);
  union { __bf16 h[4]; uint u[2]; } x;
  #pragma unroll
  for (int j = 0; j < 4; j++) x.h[j] = (__bf16)v[j];
  *(uint*)(out + (size_t)which * 65536 + i) = x.u[0];
  *(uint*)(out + (size_t)which * 65536 + i + 2) = x.u[1];
}

// ---------------------------------------------------------------------------
// histogram points into 10x10 cells. type0 = queries(kpred), type1 = keys(kact)
// ---------------------------------------------------------------------------
__global__ __launch_bounds__(256) void hist_kernel(
    const float* __restrict__ kpred, const float* __restrict__ kact,
    int* __restrict__ hist, int* __restrict__ cellpt)
{
  int p = blockIdx.x * 256 + threadIdx.x;     // 0..32767
  int type = p >> 14, idx = p & 16383;
  const float2 c = ((const float2*)(type == 0 ? kpred : kact))[idx];
  int cell = cellof(c.x) * 10 + cellof(c.y);
  int b = idx >> 12;
  atomicAdd(&hist[(type * 4 + b) * 128 + cell], 1);
  cellpt[type * 16384 + idx] = cell;
}

// ---------------------------------------------------------------------------
__global__ __launch_bounds__(256) void scan_kernel(
    const int* __restrict__ hist, int* __restrict__ strt, int* __restrict__ curs)
{
  __shared__ int sh[1024];
  int t = threadIdx.x;
  for (int i = t; i < 1024; i += 256) sh[i] = hist[i];
  __syncthreads();
  if (t < 8) {
    int run = 0;
    for (int c = 0; c < 100; c++) {
      strt[t * 128 + c] = run;
      curs[t * 128 + c] = run;
      run += sh[t * 128 + c];
    }
    strt[t * 128 + 100] = run;   // sentinel (=4096)
  }
}

// ---------------------------------------------------------------------------
// scatter: sorted index arrays, inverse perms, sorted coords (both types)
// ---------------------------------------------------------------------------
__global__ __launch_bounds__(256) void scatter_kernel(
    const float* __restrict__ kpred, const float* __restrict__ kact,
    const int* __restrict__ cellpt, int* __restrict__ curs,
    int* __restrict__ sq, int* __restrict__ invq, float* __restrict__ kpS,
    int* __restrict__ sk, int* __restrict__ invk, float* __restrict__ kaS)
{
  int p = blockIdx.x * 256 + threadIdx.x;
  int type = p >> 14, idx = p & 16383;
  int b = idx >> 12, n = idx & 4095;
  int cell = cellpt[type * 16384 + idx];
  int pos = atomicAdd(&curs[(type * 4 + b) * 128 + cell], 1);
  if (type == 0) {
    sq[b * 4096 + pos] = n;
    invq[b * 4096 + n] = pos;
    ((float2*)kpS)[b * 4096 + pos] = ((const float2*)kpred)[idx];
  } else {
    sk[b * 4096 + pos] = n;
    invk[b * 4096 + n] = pos;
    ((float2*)kaS)[b * 4096 + pos] = ((const float2*)kact)[idx];
  }
}

// ---------------------------------------------------------------------------
__global__ __launch_bounds__(256) void meansum_kernel(
    const float* __restrict__ nodes_t1, float* __restrict__ meanN)
{
  int b = blockIdx.y, chunk = blockIdx.x, c = threadIdx.x;
  const float* base = nodes_t1 + ((size_t)b * 4096 + chunk * 256) * 256 + c;
  float s = 0.f;
  for (int r = 0; r < 256; r++) s += base[(size_t)r * 256];
  atomicAdd(&meanN[b * 256 + c], s);
}

__global__ __launch_bounds__(256) void vmean_kernel(
    const float* __restrict__ meanN, const float* __restrict__ Wv,
    const float* __restrict__ bv, float* __restrict__ Vmean)
{
  __shared__ float mn[256];
  int b = blockIdx.x, d = threadIdx.x;
  mn[d] = meanN[b * 256 + d] * (1.0f / 4096.0f);
  __syncthreads();
  float s = bv[d];
  const float* w = Wv + (size_t)d * 256;
  for (int c = 0; c < 256; c++) s += mn[c] * w[c];
  Vmean[b * 256 + d] = s;
}

// ---------------------------------------------------------------------------
// GEMM: out[n][d] = sum_c A[n][c] * W[d][c] + bias[d]
// MODE 0: bf16 row-major. MODE 1: f32 row-major.
// MODE 2: bf16 transposed-scatter VT_s[b][d][inv[row]]
// MODE 3: bf16 row-scatter  out[(row&~4095)+inv[row]][d]  (sorted rows)
// ---------------------------------------------------------------------------
template<bool A_F32, int MODE>
__global__ __launch_bounds__(256) void gemm256(
    const void* __restrict__ A_, const ushort* __restrict__ W,
    const float* __restrict__ bias, void* __restrict__ out_,
    const int* __restrict__ inv)
{
  const int wid = threadIdx.x >> 6;
  const int lane = threadIdx.x & 63;
  const int q = lane & 15, g = lane >> 4;
  const int nb = blockIdx.x * 64 + (wid >> 1) * 32;
  const int db = blockIdx.y * 128 + (wid & 1) * 64;

  f32x4 acc[2][4];
  #pragma unroll
  for (int a = 0; a < 2; a++)
    #pragma unroll
    for (int b = 0; b < 4; b++) acc[a][b] = f32x4{0.f,0.f,0.f,0.f};

  const ushort* W0 = W + (size_t)(db + q) * 256 + g * 8;

  #pragma unroll
  for (int c0 = 0; c0 < 256; c0 += 32) {
    bf16x8 a0, a1;
    if constexpr (A_F32) {
      const float* Ar0 = (const float*)A_ + (size_t)(nb + q) * 256 + g * 8 + c0;
      const float* Ar1 = (const float*)A_ + (size_t)(nb + 16 + q) * 256 + g * 8 + c0;
      f32x4 u0 = *(const f32x4*)Ar0, u1 = *(const f32x4*)(Ar0 + 4);
      f32x4 w0 = *(const f32x4*)Ar1, w1 = *(const f32x4*)(Ar1 + 4);
      #pragma unroll
      for (int j = 0; j < 4; j++) {
        a0[j] = (__bf16)u0[j]; a0[4 + j] = (__bf16)u1[j];
        a1[j] = (__bf16)w0[j]; a1[4 + j] = (__bf16)w1[j];
      }
    } else {
      const ushort* Ar0 = (const ushort*)A_ + (size_t)(nb + q) * 256 + g * 8 + c0;
      const ushort* Ar1 = (const ushort*)A_ + (size_t)(nb + 16 + q) * 256 + g * 8 + c0;
      a0 = *(const bf16x8*)Ar0;
      a1 = *(const bf16x8*)Ar1;
    }
    #pragma unroll
    for (int df = 0; df < 4; df++) {
      bf16x8 w = *(const bf16x8*)(W0 + df * 16 * 256 + c0);
      acc[0][df] = MFMA16(a0, w, acc[0][df]);
      acc[1][df] = MFMA16(a1, w, acc[1][df]);
    }
  }
  #pragma unroll
  for (int df = 0; df < 4; df++) {
    float bv = bias[db + df * 16 + q];
    #pragma unroll
    for (int nf = 0; nf < 2; nf++)
      #pragma unroll
      for (int r = 0; r < 4; r++) {
        int row = nb + nf * 16 + g * 4 + r;
        int d = db + df * 16 + q;
        float val = acc[nf][df][r] + bv;
        if constexpr (MODE == 2) {
          int pos = inv[row];
          ((__bf16*)out_)[(size_t)(row >> 12) * 1048576 + (size_t)d * 4096 + pos]
              = (__bf16)val;
        } else if constexpr (MODE == 3) {
          int pos = inv[row];
          ((__bf16*)out_)[((size_t)(row & ~4095) + pos) * 256 + d] = (__bf16)val;
        } else if constexpr (MODE == 1) {
          ((float*)out_)[(size_t)row * 256 + d] = val;
        } else {
          ((__bf16*)out_)[(size_t)row * 256 + d] = (__bf16)val;
        }
      }
  }
}

// ---------------------------------------------------------------------------
// Sparse flash attention over cell-sorted queries/keys, split-K x4 in-block.
// All main-loop accesses are contiguous in sorted order (no gathers).
// ---------------------------------------------------------------------------
__global__ __launch_bounds__(256, 2) void attn_kernel(
    const ushort* __restrict__ Q,    // sorted Q_s [B*4096][256]
    const ushort* __restrict__ K,    // sorted K_s [B*4096][256]
    const ushort* __restrict__ VT,   // sorted VT_s [4][256][4096]
    const float* __restrict__ kpS,   // sorted pred coords
    const int* __restrict__ iter_idx,
    const int* __restrict__ sq,      // sorted->original query index
    const int* __restrict__ strt,    // [8][128], key segs at +4*128
    const float* __restrict__ kaS,   // sorted key coords
    const float* __restrict__ Vmean,
    __bf16* __restrict__ matched,
    float* __restrict__ out_flow, float* __restrict__ out_conf)
{
  __shared__ float stats[4][16][4];   // [wave][q][m,l,u,v]
  __shared__ float linv[16];
  __shared__ int qidx[16];
  __shared__ uint oxch[4][8][264];    // [wave][rowpair][dword] packed bf16

  const int tid = threadIdx.x;
  const int wid = tid >> 6, lane = tid & 63;
  const int q = lane & 15, g = lane >> 4;
  const int batch = blockIdx.x & 3;
  const int qt = blockIdx.x >> 2;

  const int idx = *iter_idx;
  const float win = (idx == 0) ? 64.0f : fmaxf(4.0f, ldexpf(32.0f, 1 - idx));

  const int qsrow = batch * 4096 + qt * 16;        // sorted base row
  const int qi = sq[qsrow + q];                    // original within-batch row
  if (tid < 16) qidx[tid] = sq[qsrow + tid];

  bf16x8 qf[8];
  const ushort* qptr = Q + (size_t)(qsrow + q) * 256 + g * 8;
  #pragma unroll
  for (int mf = 0; mf < 8; mf++) qf[mf] = *(const bf16x8*)(qptr + mf * 32);

  const float2 kpv = ((const float2*)kpS)[qsrow + q];
  const float pu = kpv.x, pv = kpv.y;

  // tile bbox over the 16 queries (lanes replicate across 16-groups)
  float mnu = pu, mxu = pu, mnv = pv, mxv = pv;
  #pragma unroll
  for (int off = 1; off < 16; off <<= 1) {
    mnu = fminf(mnu, __shfl_xor(mnu, off));
    mxu = fmaxf(mxu, __shfl_xor(mxu, off));
    mnv = fminf(mnv, __shfl_xor(mnv, off));
    mxv = fmaxf(mxv, __shfl_xor(mxv, off));
  }
  const int cu_lo = cellof(mnu), cu_hi = cellof(mxu);
  const int c0 = max(cellof(mnv) - 1, 0), c1 = min(cellof(mxv) + 1, 9);

  f32x4 O[16];
  #pragma unroll
  for (int i = 0; i < 16; i++) O[i] = f32x4{0.f,0.f,0.f,0.f};
  float m_run = -1e9f, l_run = 0.f, u_run = 0.f, v_run = 0.f;

  const ushort* Kbase = K + (size_t)batch * 4096 * 256;
  const ushort* VTb = VT + (size_t)batch * 1048576;
  const float2* kasb = (const float2*)kaS + (size_t)batch * 4096;
  const int* kst = strt + (4 + batch) * 128;

  for (int cu = cu_lo - 1; cu <= cu_hi + 1; ++cu) {
    if ((unsigned)cu > 9u) continue;
    const int ks = kst[cu * 10 + c0];
    const int ke = kst[cu * 10 + c1 + 1];
    for (int t = (ks & ~31) + wid * 32; t < ke; t += 128) {
      // contiguous sorted K rows t..t+31 (t multiple of 32, t <= 4064)
      const ushort* k0p = Kbase + (size_t)(t + q) * 256 + g * 8;
      const ushort* k1p = k0p + 16 * 256;
      f32x4 s0a = {0.f,0.f,0.f,0.f}, s0b = {0.f,0.f,0.f,0.f};
      f32x4 s1a = {0.f,0.f,0.f,0.f}, s1b = {0.f,0.f,0.f,0.f};
      #pragma unroll
      for (int mf = 0; mf < 8; mf += 2) {
        bf16x8 ka0 = *(const bf16x8*)(k0p + mf * 32);
        bf16x8 kb0 = *(const bf16x8*)(k0p + (mf + 1) * 32);
        bf16x8 ka1 = *(const bf16x8*)(k1p + mf * 32);
        bf16x8 kb1 = *(const bf16x8*)(k1p + (mf + 1) * 32);
        s0a = MFMA16(ka0, qf[mf], s0a);
        s0b = MFMA16(kb0, qf[mf + 1], s0b);
        s1a = MFMA16(ka1, qf[mf], s1a);
        s1b = MFMA16(kb1, qf[mf + 1], s1b);
      }

      float aus[8], avs[8], sv[8];
      #pragma unroll
      for (int r = 0; r < 4; r++) {
        int jr = t + 4 * g + r;
        float2 cc = kasb[jr];
        aus[r] = cc.x; avs[r] = cc.y;
        bool val = (jr >= ks && jr < ke);
        float du = fabsf(pu - cc.x), dv = fabsf(pv - cc.y);
        float sr = s0a[r] + s0b[r];
        sv[r] = (val && fmaxf(du, dv) < win) ? sr * 0.0625f : -1e9f;

        int jr1 = jr + 16;
        float2 c1c = kasb[jr1];
        aus[4 + r] = c1c.x; avs[4 + r] = c1c.y;
        val = (jr1 >= ks && jr1 < ke);
        du = fabsf(pu - c1c.x); dv = fabsf(pv - c1c.y);
        sr = s1a[r] + s1b[r];
        sv[4 + r] = (val && fmaxf(du, dv) < win) ? sr * 0.0625f : -1e9f;
      }

      float mt = fmaxf(fmaxf(fmaxf(sv[0], sv[1]), fmaxf(sv[2], sv[3])),
                       fmaxf(fmaxf(sv[4], sv[5]), fmaxf(sv[6], sv[7])));
      mt = fmaxf(mt, __shfl_xor(mt, 16));
      mt = fmaxf(mt, __shfl_xor(mt, 32));
      if (__any(mt > m_run)) {
        float m_new = fmaxf(m_run, mt);
        float scale = exp2f((m_run - m_new) * LOG2E);
        l_run *= scale; u_run *= scale; v_run *= scale;
        float s_r[4];
        #pragma unroll
        for (int r = 0; r < 4; r++) s_r[r] = __shfl(scale, 4 * g + r);
        #pragma unroll
        for (int df = 0; df < 16; df++)
          #pragma unroll
          for (int r = 0; r < 4; r++) O[df][r] *= s_r[r];
        m_run = m_new;
      }

      float p[8];
      #pragma unroll
      for (int i = 0; i < 8; i++) p[i] = exp2f((sv[i] - m_run) * LOG2E);
      #pragma unroll
      for (int i = 0; i < 8; i++) {
        l_run += p[i];
        u_run += p[i] * aus[i];
        v_run += p[i] * avs[i];
      }

      // pack P^T(C layout) -> A-operand layout via lane exchange
      uint d0 = packbf(p[0], p[1]), d1 = packbf(p[2], p[3]);
      uint d2 = packbf(p[4], p[5]), d3 = packbf(p[6], p[7]);
      int srcA = q + ((g & 1) << 5);
      int srcB = srcA + 16;
      uint x0 = (uint)__shfl((int)d0, srcA), x1 = (uint)__shfl((int)d1, srcA);
      uint x2 = (uint)__shfl((int)d0, srcB), x3 = (uint)__shfl((int)d1, srcB);
      uint y0 = (uint)__shfl((int)d2, srcA), y1 = (uint)__shfl((int)d3, srcA);
      uint y2 = (uint)__shfl((int)d2, srcB), y3 = (uint)__shfl((int)d3, srcB);
      union { uint i[4]; bf16x8 v; } af;
      bool lo = (g < 2);
      af.i[0] = lo ? x0 : y0; af.i[1] = lo ? x1 : y1;
      af.i[2] = lo ? x2 : y2; af.i[3] = lo ? x3 : y3;

      #pragma unroll
      for (int df = 0; df < 16; df++) {
        bf16x8 vf = *(const bf16x8*)(VTb + (size_t)(df * 16 + q) * 4096 + t + g * 8);
        O[df] = MFMA16(af.v, vf, O[df]);
      }
    }
  }

  // per-wave reduction across the 4 lane groups
  l_run += __shfl_xor(l_run, 16); l_run += __shfl_xor(l_run, 32);
  u_run += __shfl_xor(u_run, 16); u_run += __shfl_xor(u_run, 32);
  v_run += __shfl_xor(v_run, 16); v_run += __shfl_xor(v_run, 32);

  if (g == 0) {
    stats[wid][q][0] = m_run; stats[wid][q][1] = l_run;
    stats[wid][q][2] = u_run; stats[wid][q][3] = v_run;
  }
  __syncthreads();

  if (wid == 0 && lane < 16) {
    float m0 = stats[0][q][0], m1 = stats[1][q][0];
    float m2 = stats[2][q][0], m3 = stats[3][q][0];
    float ms = fmaxf(fmaxf(m0, m1), fmaxf(m2, m3));
    float s0 = exp2f((m0 - ms) * LOG2E), s1 = exp2f((m1 - ms) * LOG2E);
    float s2 = exp2f((m2 - ms) * LOG2E), s3 = exp2f((m3 - ms) * LOG2E);
    float ls = s0 * stats[0][q][1] + s1 * stats[1][q][1]
             + s2 * stats[2][q][1] + s3 * stats[3][q][1];
    float us = s0 * stats[0][q][2] + s1 * stats[1][q][2]
             + s2 * stats[2][q][2] + s3 * stats[3][q][2];
    float vs = s0 * stats[0][q][3] + s1 * stats[1][q][3]
             + s2 * stats[2][q][3] + s3 * stats[3][q][3];
    bool degen = (ms <= -5e8f);
    float il = degen ? 0.f : 1.0f / ls;
    linv[q] = il;
    float conf = degen ? 0.f : 1.0f;
    int row = batch * 4096 + qi;
    float fu = (us * il - pu) * conf, fv = (vs * il - pv) * conf;
    ((float2*)out_flow)[row] = float2{fu, fv};
    out_conf[row] = conf;
  }

  // every wave: scale own O to combined max, write packed bf16 to LDS
  {
    float m0 = stats[0][q][0], m1 = stats[1][q][0];
    float m2 = stats[2][q][0], m3 = stats[3][q][0];
    float ms = fmaxf(fmaxf(m0, m1), fmaxf(m2, m3));
    float scale_q = exp2f((m_run - ms) * LOG2E);
    float s_r[4];
    #pragma unroll
    for (int r = 0; r < 4; r++) s_r[r] = __shfl(scale_q, 4 * g + r);
    #pragma unroll
    for (int df = 0; df < 16; df++) {
      f32x4 o = O[df];
      o[0] *= s_r[0]; o[1] *= s_r[1]; o[2] *= s_r[2]; o[3] *= s_r[3];
      oxch[wid][2 * g + 0][df * 16 + q] = packbf(o[0], o[1]);
      oxch[wid][2 * g + 1][df * 16 + q] = packbf(o[2], o[3]);
    }
  }
  __syncthreads();

  // combine 4 partials, write matched (scattered rows; Vmean if degenerate)
  {
    const int rr = tid >> 4, dl = tid & 15;
    const int rp = rr >> 1, sh = (rr & 1) << 4;
    const float il = linv[rr];
    const bool degen = (il == 0.f);
    const float* Vm = Vmean + batch * 256;
    __bf16* mrow = matched + ((size_t)batch * 4096 + qidx[rr]) * 256;
    #pragma unroll
    for (int j = 0; j < 16; j++) {
      int dw = dl + 16 * j;
      float s = upbf(oxch[0][rp][dw], sh) + upbf(oxch[1][rp][dw], sh)
              + upbf(oxch[2][rp][dw], sh) + upbf(oxch[3][rp][dw], sh);
      mrow[dw] = (__bf16)(degen ? Vm[dw] : s * il);
    }
  }
}

// ---------------------------------------------------------------------------
__global__ __launch_bounds__(256) void geo_kernel(
    const float* __restrict__ flow, const float* __restrict__ conf_in,
    const float* __restrict__ Wg1, const float* __restrict__ bg1,
    const float* __restrict__ Wg2, const float* __restrict__ bg2,
    float* __restrict__ out_geo)
{
  __shared__ float w1[32][3], b1[32], b2[32];
  __shared__ __align__(16) float w2[32][32];
  int tid = threadIdx.x;
  for (int i = tid; i < 96; i += 256) w1[i / 3][i % 3] = Wg1[i];
  if (tid < 32) { b1[tid] = bg1[tid]; b2[tid] = bg2[tid]; }
  for (int i = tid; i < 1024; i += 256) w2[i / 32][i % 32] = Wg2[i];
  __syncthreads();

  int row = blockIdx.x * 256 + tid;
  float2 f = ((const float2*)flow)[row];
  float c = conf_in[row];
  float h[32];
  #pragma unroll
  for (int j = 0; j < 32; j++) {
    float x = w1[j][0] * f.x + w1[j][1] * f.y + w1[j][2] * c + b1[j];
    h[j] = x / (1.f + __expf(-x));
  }
  #pragma unroll
  for (int o = 0; o < 32; o += 2) {
    float s0 = b2[o], s1 = b2[o + 1];
    #pragma unroll
    for (int j = 0; j < 32; j += 4) {
      f32x4 wa = *(const f32x4*)&w2[o][j];
      f32x4 wb = *(const f32x4*)&w2[o + 1][j];
      s0 += wa[0]*h[j] + wa[1]*h[j+1] + wa[2]*h[j+2] + wa[3]*h[j+3];
      s1 += wb[0]*h[j] + wb[1]*h[j+1] + wb[2]*h[j+2] + wb[3]*h[j+3];
    }
    ((float2*)out_geo)[((size_t)row * 32 + o) >> 1] = float2{s0, s1};
  }
}

// ---------------------------------------------------------------------------
extern "C" void kernel_launch(void* const* d_in, const int* in_sizes, int n_in,
                              void* d_out, int out_size, void* d_ws, size_t ws_size,
                              hipStream_t stream) {
  const float* nodes_t  = (const float*)d_in[0];
  const float* nodes_t1 = (const float*)d_in[1];
  const float* kpred    = (const float*)d_in[2];
  const float* kact     = (const float*)d_in[3];
  const float* Wq = (const float*)d_in[4];  const float* bq = (const float*)d_in[5];
  const float* Wk = (const float*)d_in[6];  const float* bk = (const float*)d_in[7];
  const float* Wv = (const float*)d_in[8];  const float* bv = (const float*)d_in[9];
  const float* Wm = (const float*)d_in[10]; const float* bm = (const float*)d_in[11];
  const float* Wg1= (const float*)d_in[12]; const float* bg1= (const float*)d_in[13];
  const float* Wg2= (const float*)d_in[14]; const float* bg2= (const float*)d_in[15];
  const int* iter = (const int*)d_in[16];

  float* out_merged = (float*)d_out;                 // 4*4096*256
  float* out_geo  = out_merged + 4 * 4096 * 256;     // 4*4096*32
  float* out_flow = out_geo + 4 * 4096 * 32;         // 4*4096*2
  float* out_conf = out_flow + 4 * 4096 * 2;         // 4*4096

  ushort* wsQ   = (ushort*)d_ws;        // bf16 4194304 el each (sorted)
  ushort* wsK   = wsQ + 4194304;        // sorted K_s
  ushort* wsVT  = wsK + 4194304;        // VT_s [4][256][4096] sorted keys
  ushort* wsM   = wsVT + 4194304;
  ushort* wsW   = wsM + 4194304;        // bf16 4*65536
  float*  kaS   = (float*)(wsW + 262144);   // 32768 f32
  float*  kpS   = kaS + 32768;              // 32768 f32
  float*  meanN = kpS + 32768;              // 1024
  float*  Vmean = meanN + 1024;             // 1024
  int*    hist  = (int*)(Vmean + 1024);     // 1024
  int*    strt  = hist + 1024;              // 1024
  int*    curs  = strt + 1024;              // 1024
  int*    cellpt= curs + 1024;              // 32768
  int*    sq    = cellpt + 32768;           // 16384
  int*    sk    = sq + 16384;               // 16384
  int*    invk  = sk + 16384;               // 16384
  int*    invq  = invk + 16384;             // 16384

  zero_ws<<<1, 256, 0, stream>>>(hist, curs, meanN);
  dim3 cg(64, 4, 1);
  cast_weights<<<cg, 256, 0, stream>>>(Wq, Wk, Wv, Wm, (__bf16*)wsW);
  hist_kernel<<<128, 256, 0, stream>>>(kpred, kact, hist, cellpt);
  scan_kernel<<<1, 256, 0, stream>>>(hist, strt, curs);
  scatter_kernel<<<128, 256, 0, stream>>>(kpred, kact, cellpt, curs,
                                          sq, invq, kpS, sk, invk, kaS);
  dim3 mg(16, 4, 1);
  meansum_kernel<<<mg, 256, 0, stream>>>(nodes_t1, meanN);
  vmean_kernel<<<4, 256, 0, stream>>>(meanN, Wv, bv, Vmean);

  dim3 gg(256, 2, 1);
  gemm256<true, 3><<<gg, 256, 0, stream>>>(nodes_t,  wsW,          bq, wsQ, invq);
  gemm256<true, 3><<<gg, 256, 0, stream>>>(nodes_t1, wsW + 65536,  bk, wsK, invk);
  gemm256<true, 2><<<gg, 256, 0, stream>>>(nodes_t1, wsW + 131072, bv, wsVT, invk);
  attn_kernel<<<1024, 256, 0, stream>>>(wsQ, wsK, wsVT, kpS, iter,
                                        sq, strt, kaS, Vmean,
                                        (__bf16*)wsM, out_flow, out_conf);
  gemm256<false, 1><<<gg, 256, 0, stream>>>(wsM, wsW + 196608, bm, out_merged, nullptr);
  geo_kernel<<<64, 256, 0, stream>>>(out_flow, out_conf, Wg1, bg1, Wg2, bg2, out_geo);
}